// Round 5
// baseline (740.596 us; speedup 1.0000x reference)
//
#include <hip/hip_runtime.h>
#include <hip/hip_cooperative_groups.h>
#include <math.h>

namespace cg = cooperative_groups;

// Problem constants (from reference)
constexpr int R  = 5;
constexpr int E  = 50000;   // divisible by 16 (pass1 tiling relies on this)
constexpr int NU = 20000;
constexpr int NI = 20000;
constexpr int NF = 4;
constexpr int DN = 16;
constexpr int DR = 64;
constexpr int DO = 64;
constexpr float TAU = 0.5f;
constexpr float INV_TAU = 2.0f;

// Phase unit counts
constexpr int NXF_TILES  = (NU + 63) / 64;          // 313 per (r,side); NU==NI
constexpr int NXF_UNITS  = NXF_TILES * R * 2;       // 3130
constexpr int P1_TILES   = E / 16;                  // 3125 per r
constexpr int P1_UNITS   = P1_TILES * R;            // 15625
constexpr int P2_TILES   = (E + 63) / 64;           // 782 per r
constexpr int P2_UNITS   = P2_TILES * R;            // 3910
constexpr long long ZTOT4 = (long long)(NU + NI) * (DN + 1) / 4;  // 170000 float4
constexpr long long P3_TOT = (long long)(NU + NI) * DO;

// ---------------- Fused cooperative kernel: all phases, one launch ----------
// P0: zero accumulators + node transform   | grid.sync
// P1: per-edge blended + norms (atomics)   | grid.sync
// P2: per-edge messages -> node msg atomics| grid.sync
// P3: leaky-relu + FC epilogue
// Phase bodies are byte-identical to the individually-verified split kernels.
__global__ __launch_bounds__(256) void fused_kernel(
    const float* __restrict__ user_h,      // (NF,R,NU,DN)
    const float* __restrict__ item_h,      // (NF,R,NI,DN)
    const float* __restrict__ user_hsum,   // (R,NU,NF,DN)
    const float* __restrict__ item_hsum,   // (R,NI,NF,DN)
    const float* __restrict__ review_feat, // (R,E,NF,DR)
    const float* __restrict__ prototypes,  // (NF,DR)
    const float* __restrict__ eta,         // (R,E)
    const float* __restrict__ node_w_fwd,  // (R,DN,DN)
    const float* __restrict__ review_w_fwd,// (R,DN,DR)
    const float* __restrict__ node_w_rev,  // (R,DN,DN)
    const float* __restrict__ review_w_rev,// (R,DN,DR)
    const float* __restrict__ ufc_w,       // (DO,DN)
    const float* __restrict__ ufc_b,       // (DO)
    const float* __restrict__ ifc_w,       // (DO,DN)
    const float* __restrict__ ifc_b,       // (DO)
    const int*   __restrict__ edge_src,    // (R,E)
    const int*   __restrict__ edge_dst,    // (R,E)
    const int*   __restrict__ kptr,
    float* __restrict__ norm_user,         // (NU)          } zero region start
    float* __restrict__ norm_item,         // (NI)
    float* __restrict__ user_msg,          // (NU,DN)
    float* __restrict__ item_msg,          // (NI,DN)       } zero region end
    float* __restrict__ blended,           // (R*E)
    float* __restrict__ hu_t,              // (R,NU,DN)
    float* __restrict__ hi_t,              // (R,NI,DN)
    float* __restrict__ int_dist,          // (R*E)
    float* __restrict__ ufeat,             // (NU,DO)
    float* __restrict__ ifeat)             // (NI,DO)
{
    cg::grid_group grid = cg::this_grid();

    const int t    = threadIdx.x;
    const int lane = t & 63;
    const int w    = t >> 6;
    const int k    = *kptr;

    // Shared phase-union LDS block (max user: P2 = 6592 floats = 25.75 KB)
    __shared__ __align__(16) float smem[6592];

    // ================= P0a: zero accumulators =================
    {
        float4 z = make_float4(0.f, 0.f, 0.f, 0.f);
        for (long long i = (long long)blockIdx.x * 256 + t; i < ZTOT4;
             i += (long long)gridDim.x * 256)
            ((float4*)norm_user)[i] = z;
    }

    // ================= P0b: node transform =================
    {
        float* lds_h = smem;          // 64*16 = 1024
        float* lds_w = smem + 1024;   // 16*17 = 272
        for (int unit = blockIdx.x; unit < NXF_UNITS; unit += gridDim.x) {
            const int n0   = (unit % NXF_TILES) * 64;
            const int rs   = unit / NXF_TILES;
            const int r    = rs % R;
            const int side = rs / R;
            const int N    = side ? NI : NU;
            const float* h    = side ? item_h : user_h;
            const float* wsrc = side ? node_w_rev : node_w_fwd;
            float* out        = side ? hi_t : hu_t;

            {
                const int o = t >> 4, d = t & 15;
                lds_w[o * 17 + d] = wsrc[((long long)r * DN + o) * DN + d];
            }
            {
                const int row = t >> 2, c = t & 3;
                if (n0 + row < N) {
                    const float4 v = *(const float4*)(h +
                        (((long long)k * R + r) * N + n0 + row) * DN + c * 4);
                    *(float4*)&lds_h[t * 4] = v;
                }
            }
            __syncthreads();

            const int o = t & 15;
#pragma unroll
            for (int p = 0; p < 4; ++p) {
                const int nl = p * 16 + (t >> 4);
                const int n = n0 + nl;
                if (n < N) {
                    float acc = 0.f;
#pragma unroll
                    for (int d = 0; d < DN; ++d)
                        acc += lds_h[nl * 16 + d] * lds_w[o * 17 + d];
                    out[((long long)r * N + n) * DN + o] = acc;
                }
            }
            __syncthreads();   // LDS reused next unit
        }
    }

    grid.sync();

    // ================= P1: per-edge blended + norms =================
    {
        const int e  = lane >> 4;       // 0..3
        const int le = lane & 15;       // 0..15
        const int f  = le >> 2;         // 0..3
        const int j  = le & 3;          // 0..3

        for (int unit = blockIdx.x; unit < P1_UNITS; unit += gridDim.x) {
            const int r    = unit / P1_TILES;
            const int tile = unit % P1_TILES;
            const int base = (tile * 4 + w) * 4;
            const int ee   = base + e;
            const long long re = (long long)r * E + ee;

            const int src = edge_src[re];
            const int dst = edge_dst[re];

            // sim_k (l2norm dot over DN=16): quad f==0 only
            float na = 0.f, nb = 0.f, ab = 0.f;
            if (f == 0) {
                const float4 ua = *(const float4*)(user_h +
                    (((long long)k * R + r) * NU + src) * DN + j * 4);
                const float4 ia = *(const float4*)(item_h +
                    (((long long)k * R + r) * NI + dst) * DN + j * 4);
                na = ua.x*ua.x + ua.y*ua.y + ua.z*ua.z + ua.w*ua.w;
                nb = ia.x*ia.x + ia.y*ia.y + ia.z*ia.z + ia.w*ia.w;
                ab = ua.x*ia.x + ua.y*ia.y + ua.z*ia.z + ua.w*ia.w;
            }
            na += __shfl_xor(na, 1, 64); na += __shfl_xor(na, 2, 64);
            nb += __shfl_xor(nb, 1, 64); nb += __shfl_xor(nb, 2, 64);
            ab += __shfl_xor(ab, 1, 64); ab += __shfl_xor(ab, 2, 64);

            // sim_all over hsum rows
            const float4 rs4 = *(const float4*)(user_hsum +
                ((long long)r * NU + src) * (NF * DN) + le * 4);
            const float4 cs4 = *(const float4*)(item_hsum +
                ((long long)r * NI + dst) * (NF * DN) + le * 4);
            float p = rs4.x*cs4.x + rs4.y*cs4.y + rs4.z*cs4.z + rs4.w*cs4.w;
            p += __shfl_xor(p, 1, 64); p += __shfl_xor(p, 2, 64);
            float denom_sim = __expf(p * INV_TAU);
            denom_sim += __shfl_xor(denom_sim, 4, 64);
            denom_sim += __shfl_xor(denom_sim, 8, 64);

            // anchors
            const float4* rf4 = (const float4*)review_feat + re * (NF * DR / 4);
            const float4* pr4 = (const float4*)prototypes;
            float q = 0.f;
#pragma unroll
            for (int c = 0; c < 4; ++c) {
                const float4 a = rf4[f * 16 + c * 4 + j];
                const float4 b = pr4[f * 16 + c * 4 + j];
                q += a.x*b.x + a.y*b.y + a.z*b.z + a.w*b.w;
            }
            q += __shfl_xor(q, 1, 64); q += __shfl_xor(q, 2, 64);
            float ea = __expf(q * INV_TAU);
            float denom_anc = ea;
            denom_anc += __shfl_xor(denom_anc, 4, 64);
            denom_anc += __shfl_xor(denom_anc, 8, 64);
            const float ea_k = __shfl(ea, (lane & 48) | (k << 2), 64);

            if (le == 0) {
                const float sim_k = ab /
                    (fmaxf(sqrtf(na), 1e-12f) * fmaxf(sqrtf(nb), 1e-12f)) * INV_TAU;
                const float exp_anchor = ea_k / denom_anc;
                const float exp_sim    = __expf(sim_k) / denom_sim;
                const float g = 1.0f / (1.0f + __expf(-eta[re]));
                const float bl = g * exp_anchor + (1.0f - g) * exp_sim;
                blended[re] = bl;
                atomicAdd(&norm_user[src], bl);
                atomicAdd(&norm_item[dst], bl);
            }
        }
    }

    grid.sync();

    // ================= P2: per-edge messages -> node msg atomics =================
    {
        constexpr int EPB = 64;
        constexpr int RSTRIDE = 68;
        constexpr int TSTRIDE = 17;
        float* wf    = smem;                 // 1024
        float* wr    = smem + 1024;          // 1024
        float* rf    = smem + 2048;          // 64*68 = 4352 (also transpose buf)
        float* wgt_s = smem + 6400;          // 64
        int*   src_s = (int*)(smem + 6464);  // 64
        int*   dst_s = (int*)(smem + 6528);  // 64

        for (int unit = blockIdx.x; unit < P2_UNITS; unit += gridDim.x) {
            const int r  = unit / P2_TILES;
            const int e0 = (unit % P2_TILES) * EPB;

            // stage weights
            {
                const int i = t * 4;
                *(float4*)&wf[i] = *(const float4*)(review_w_fwd + (long long)r * (DN * DR) + i);
                *(float4*)&wr[i] = *(const float4*)(review_w_rev + (long long)r * (DN * DR) + i);
            }
            // stage rf tile
            {
                const int row = t >> 2;
                const int c0  = (t & 3) * 16;
                const int ee  = e0 + row;
                if (ee < E) {
                    const float4* s = (const float4*)(review_feat +
                        (((long long)r * E + ee) * NF + k) * DR + c0);
                    float4* d = (float4*)&rf[row * RSTRIDE + c0];
                    d[0] = s[0]; d[1] = s[1]; d[2] = s[2]; d[3] = s[3];
                }
            }
            // stage per-edge scalars + int_dist
            if (t < EPB) {
                const int ee = e0 + t;
                if (ee < E) {
                    const long long re = (long long)r * E + ee;
                    const int s  = edge_src[re];
                    const int d2 = edge_dst[re];
                    src_s[t] = s; dst_s[t] = d2;
                    const float wgt = blended[re] * rsqrtf(norm_user[s] * norm_item[d2]);
                    wgt_s[t] = wgt;
                    int_dist[re] = wgt;
                }
            }
            __syncthreads();

            const int ee = e0 + lane;
            const int ob = w * 4;
            float accf[4] = {0.f, 0.f, 0.f, 0.f};
            float accr[4] = {0.f, 0.f, 0.f, 0.f};

            const float* rfrow = &rf[lane * RSTRIDE];
#pragma unroll 4
            for (int c = 0; c < 16; ++c) {
                const float4 a = *(const float4*)&rfrow[c * 4];
#pragma unroll
                for (int jj = 0; jj < 4; ++jj) {
                    const float4 bf = *(const float4*)&wf[(ob + jj) * DR + c * 4];
                    const float4 br = *(const float4*)&wr[(ob + jj) * DR + c * 4];
                    accf[jj] += a.x*bf.x + a.y*bf.y + a.z*bf.z + a.w*bf.w;
                    accr[jj] += a.x*br.x + a.y*br.y + a.z*br.z + a.w*br.w;
                }
            }

            float msgf[4] = {0.f, 0.f, 0.f, 0.f};
            float msgr[4] = {0.f, 0.f, 0.f, 0.f};
            if (ee < E) {
                const int src = src_s[lane];
                const int dst = dst_s[lane];
                const float wgt = wgt_s[lane];
                const float4 hu = *(const float4*)(hu_t + ((long long)r * NU + src) * DN + ob);
                const float4 hi = *(const float4*)(hi_t + ((long long)r * NI + dst) * DN + ob);
                msgf[0] = (accf[0] + hu.x) * wgt;  msgf[1] = (accf[1] + hu.y) * wgt;
                msgf[2] = (accf[2] + hu.z) * wgt;  msgf[3] = (accf[3] + hu.w) * wgt;
                msgr[0] = (accr[0] + hi.x) * wgt;  msgr[1] = (accr[1] + hi.y) * wgt;
                msgr[2] = (accr[2] + hi.z) * wgt;  msgr[3] = (accr[3] + hi.w) * wgt;
            }

            __syncthreads();
            float* af = rf;
            float* ar = rf + EPB * TSTRIDE;
#pragma unroll
            for (int jj = 0; jj < 4; ++jj) {
                af[lane * TSTRIDE + ob + jj] = msgf[jj];
                ar[lane * TSTRIDE + ob + jj] = msgr[jj];
            }
            __syncthreads();

            const int o  = t & 15;
            const int eb = t >> 4;
#pragma unroll
            for (int p = 0; p < 4; ++p) {
                const int el = eb + p * 16;
                if (e0 + el < E) {
                    atomicAdd(&item_msg[(long long)dst_s[el] * DN + o], af[el * TSTRIDE + o]);
                    atomicAdd(&user_msg[(long long)src_s[el] * DN + o], ar[el * TSTRIDE + o]);
                }
            }
            __syncthreads();   // LDS reused next unit
        }
    }

    grid.sync();

    // ================= P3: leaky-relu + FC epilogue =================
    {
        const long long nu_total = (long long)NU * DO;
        for (long long u = (long long)blockIdx.x * 256 + t; u < P3_TOT;
             u += (long long)gridDim.x * 256) {
            const bool is_item = (u >= nu_total);
            const long long tt = is_item ? (u - nu_total) : u;
            const int j = (int)(tt & 63);
            const long long n = tt >> 6;

            const float* msg  = (is_item ? item_msg : user_msg) + n * DN;
            const float* wrow = (is_item ? ifc_w : ufc_w) + (long long)j * DN;
            float acc = (is_item ? ifc_b : ufc_b)[j];
#pragma unroll
            for (int d = 0; d < DN; ++d) {
                float x = msg[d];
                x = (x > 0.f) ? x : 0.1f * x;
                acc += x * wrow[d];
            }
            (is_item ? ifeat : ufeat)[tt] = acc;
        }
    }
}

extern "C" void kernel_launch(void* const* d_in, const int* in_sizes, int n_in,
                              void* d_out, int out_size, void* d_ws, size_t ws_size,
                              hipStream_t stream) {
    const float* user_h       = (const float*)d_in[0];
    const float* item_h       = (const float*)d_in[1];
    const float* user_hsum    = (const float*)d_in[2];
    const float* item_hsum    = (const float*)d_in[3];
    const float* review_feat  = (const float*)d_in[4];
    const float* prototypes   = (const float*)d_in[5];
    const float* eta          = (const float*)d_in[6];
    const float* node_w_fwd   = (const float*)d_in[7];
    const float* review_w_fwd = (const float*)d_in[8];
    const float* node_w_rev   = (const float*)d_in[9];
    const float* review_w_rev = (const float*)d_in[10];
    const float* ufc_w        = (const float*)d_in[11];
    const float* ufc_b        = (const float*)d_in[12];
    const float* ifc_w        = (const float*)d_in[13];
    const float* ifc_b        = (const float*)d_in[14];
    const int*   edge_src     = (const int*)d_in[15];
    const int*   edge_dst     = (const int*)d_in[16];
    const int*   kptr         = (const int*)d_in[17];

    // Workspace layout: zero region (norms + msgs) first and contiguous.
    float* ws = (float*)d_ws;
    float* norm_user = ws;                                    // NU   } zeroed in P0
    float* norm_item = norm_user + NU;                        // NI   }
    float* user_msg  = norm_item + NI;                        // NU*DN}
    float* item_msg  = user_msg + (long long)NU * DN;         // NI*DN}
    float* blended   = item_msg + (long long)NI * DN;         // R*E
    float* hu_t      = blended + (long long)R * E;            // R*NU*DN
    float* hi_t      = hu_t + (long long)R * NU * DN;         // R*NI*DN

    float* ufeat    = (float*)d_out;
    float* ifeat    = ufeat + (long long)NU * DO;
    float* int_dist = ifeat + (long long)NI * DO;

    // Cooperative grid sizing: blocks/CU from the occupancy API (residency-safe)
    int nbpc = 0;
    if (hipOccupancyMaxActiveBlocksPerMultiprocessor(&nbpc, fused_kernel, 256, 0)
            != hipSuccess || nbpc < 1)
        nbpc = 1;
    if (nbpc > 8) nbpc = 8;
    const int nblk = nbpc * 256;    // 256 CUs on MI355X

    void* args[] = {
        (void*)&user_h, (void*)&item_h, (void*)&user_hsum, (void*)&item_hsum,
        (void*)&review_feat, (void*)&prototypes, (void*)&eta,
        (void*)&node_w_fwd, (void*)&review_w_fwd, (void*)&node_w_rev,
        (void*)&review_w_rev, (void*)&ufc_w, (void*)&ufc_b, (void*)&ifc_w,
        (void*)&ifc_b, (void*)&edge_src, (void*)&edge_dst, (void*)&kptr,
        (void*)&norm_user, (void*)&norm_item, (void*)&user_msg, (void*)&item_msg,
        (void*)&blended, (void*)&hu_t, (void*)&hi_t, (void*)&int_dist,
        (void*)&ufeat, (void*)&ifeat
    };
    hipLaunchCooperativeKernel(fused_kernel, dim3(nblk), dim3(256), args, 0, stream);
}